// Round 4
// baseline (2081.496 us; speedup 1.0000x reference)
//
#include <hip/hip_runtime.h>
#include <cstdint>
#include <cstddef>

// GIN 2-layer + mean-pool + head. bf16 features, fp32 accumulation.
// Features stored DIM-CHUNK-MAJOR: F[c][node][16] so each chunk region
// (3.2 MB) is L2-resident during aggregation. Aggregation = bucketed PUSH
// with LDS fp32 accumulators (no slots, no global atomics). GEMMs: MFMA bf16.

namespace {

constexpr int N_NODES  = 100000;
constexpr int N_EDGES  = 1600000;
constexpr int N_GRAPHS = 512;
constexpr int NBUCK    = (N_NODES + 511) / 512;   // 196 dst buckets of 512 nodes
constexpr int BCAP     = 9216;                    // mean 8192, sigma ~90: +11 sigma
constexpr size_t CHN   = size_t(N_NODES) * 16;    // elems per 16-dim chunk region

constexpr size_t algn(size_t x){ return (x + size_t(255)) & ~size_t(255); }

constexpr size_t OFF_GOFF  = 0;                                       // 513 ints
constexpr size_t OFF_FLAG  = algn(OFF_GOFF + 513*4);                  // 1 int
constexpr size_t OFF_GCUR  = algn(OFF_FLAG + 4);                      // NBUCK ints
constexpr size_t OFF_BKT   = algn(OFF_GCUR + size_t(NBUCK)*4);        // NBUCK*BCAP u32
constexpr size_t OFF_XC    = algn(OFF_BKT  + size_t(NBUCK)*BCAP*4);   // 4 regions bf16
constexpr size_t OFF_WT1A  = algn(OFF_XC   + 4*CHN*2);                // 128*64 bf16
constexpr size_t OFF_WT1B  = algn(OFF_WT1A + 8192*2);                 // 128*128 bf16
constexpr size_t OFF_WT2A  = algn(OFF_WT1B + 16384*2);
constexpr size_t OFF_WT2B  = algn(OFF_WT2A + 16384*2);
constexpr size_t OFF_F0    = algn(OFF_WT2B + 16384*2);                // 4 regions
constexpr size_t OFF_H1    = algn(OFF_F0   + 4*CHN*2);                // 8 regions
constexpr size_t OFF_H2    = algn(OFF_H1   + 8*CHN*2);                // 8 regions
constexpr size_t OFF_H3    = algn(OFF_H2   + 8*CHN*2);                // 8 regions
constexpr size_t WS_NEED   = OFF_H3 + 8*CHN*2;                        // ~103 MB

// ---- helpers ---------------------------------------------------------------
__device__ __forceinline__ int load_idx(const void* p, size_t i, bool wide) {
    return wide ? (int)((const long long*)p)[i] : ((const int*)p)[i];
}

__device__ __forceinline__ uint16_t f32_to_bf16(float f) {
    union { float f; uint32_t i; } v; v.f = f;
    uint32_t u = v.i;
    uint32_t r = (u + 0x7FFFu + ((u >> 16) & 1u)) >> 16;   // RNE
    return (uint16_t)r;
}

__device__ __forceinline__ float bf16_to_f32(uint16_t h) {
    union { uint32_t i; float f; } v; v.i = ((uint32_t)h) << 16;
    return v.f;
}

__device__ __forceinline__ void unpack2(uint32_t u, float& a, float& b) {
    union { uint32_t i; float f; } x, y;
    x.i = u << 16;            // low half  = elem 0
    y.i = u & 0xFFFF0000u;    // high half = elem 1
    a = x.f; b = y.f;
}

__device__ __forceinline__ void unpack16(uint4 w0, uint4 w1, float* v) {
    unpack2(w0.x, v[0], v[1]);  unpack2(w0.y, v[2], v[3]);
    unpack2(w0.z, v[4], v[5]);  unpack2(w0.w, v[6], v[7]);
    unpack2(w1.x, v[8], v[9]);  unpack2(w1.y, v[10], v[11]);
    unpack2(w1.z, v[12], v[13]); unpack2(w1.w, v[14], v[15]);
}

// ---- index width detection -------------------------------------------------
// int64 layout -> every odd 32-bit word (high half) is 0. flag==0 -> wide.
__global__ void detect_wide(const int* __restrict__ ei, int* __restrict__ flag) {
    int v = ei[2 * threadIdx.x + 1];
    if (v != 0) atomicOr(flag, 1);
}

// ---- partition edges into dst-range buckets, packed (src<<9 | dst_local) ---
__global__ void bucket_edges(const void* __restrict__ ei, const int* __restrict__ flag,
                             int* __restrict__ gcur, uint32_t* __restrict__ bkt) {
    __shared__ int lcnt[NBUCK];
    __shared__ int lbase[NBUCK];
    const bool wide = (*flag == 0);
    const int tid = threadIdx.x;
    for (int i = tid; i < NBUCK; i += 256) lcnt[i] = 0;
    __syncthreads();
    int es[16], ed[16], er[16];
    const int base = blockIdx.x * 4096;
    #pragma unroll
    for (int i = 0; i < 16; ++i) {
        int e = base + i * 256 + tid;
        if (e < N_EDGES) {
            es[i] = load_idx(ei, size_t(e), wide);
            ed[i] = load_idx(ei, size_t(N_EDGES) + e, wide);
            er[i] = atomicAdd(&lcnt[ed[i] >> 9], 1);
        } else ed[i] = -1;
    }
    __syncthreads();
    for (int i = tid; i < NBUCK; i += 256)
        lbase[i] = atomicAdd(&gcur[i], lcnt[i]);
    __syncthreads();
    #pragma unroll
    for (int i = 0; i < 16; ++i) {
        if (ed[i] < 0) continue;
        int b = ed[i] >> 9;
        int idx = lbase[b] + er[i];
        if (idx < BCAP)
            bkt[size_t(b) * BCAP + idx] = ((uint32_t)es[i] << 9) | (uint32_t)(ed[i] & 511);
    }
}

// ---- graph offsets via binary search (batch is sorted) ---------------------
__global__ void goff_search(const void* __restrict__ bat, const int* __restrict__ flag,
                            int* __restrict__ goff) {
    int g = threadIdx.x;
    if (g > N_GRAPHS) return;
    const bool wide = (*flag == 0);
    int lo = 0, hi = N_NODES;
    while (lo < hi) {
        int mid = (lo + hi) >> 1;
        if (load_idx(bat, size_t(mid), wide) < g) lo = mid + 1; else hi = mid;
    }
    goff[g] = lo;
}

// ---- x fp32 [N,64] -> chunk-major bf16 XC[4][N][16] ------------------------
__global__ void cvt_x_chunk(const float* __restrict__ x, uint16_t* __restrict__ xc) {
    int idx = blockIdx.x * 256 + threadIdx.x;     // 400000 total
    if (idx >= 4 * N_NODES) return;
    int c = idx / N_NODES, n = idx - c * N_NODES;
    const float* xp = x + size_t(n) * 64 + c * 16;
    uint32_t o[8];
    #pragma unroll
    for (int j = 0; j < 8; ++j)
        o[j] = (uint32_t)f32_to_bf16(xp[2*j]) | ((uint32_t)f32_to_bf16(xp[2*j+1]) << 16);
    uint16_t* op = xc + size_t(c) * CHN + size_t(n) * 16;
    *reinterpret_cast<uint4*>(op)     = make_uint4(o[0], o[1], o[2], o[3]);
    *reinterpret_cast<uint4*>(op + 8) = make_uint4(o[4], o[5], o[6], o[7]);
}

// transpose W[K][128] fp32 -> WT[n*K + k] bf16 (four weights in one kernel)
__global__ void cvt_weights(const float* __restrict__ W1a, const float* __restrict__ W1b,
                            const float* __restrict__ W2a, const float* __restrict__ W2b,
                            uint16_t* __restrict__ T1a, uint16_t* __restrict__ T1b,
                            uint16_t* __restrict__ T2a, uint16_t* __restrict__ T2b) {
    int idx = blockIdx.x * 256 + threadIdx.x;    // 57344 total
    const float* W; uint16_t* T; int K; int local;
    if (idx < 8192)        { W = W1a; T = T1a; K = 64;  local = idx; }
    else if (idx < 24576)  { W = W1b; T = T1b; K = 128; local = idx - 8192; }
    else if (idx < 40960)  { W = W2a; T = T2a; K = 128; local = idx - 24576; }
    else                   { W = W2b; T = T2b; K = 128; local = idx - 40960; }
    int k = local >> 7, n = local & 127;
    T[n * K + k] = f32_to_bf16(W[local]);
}

// ---- push aggregation: out[c][i] = x[c][i] + sum_{j->i} x[c][j] ------------
// Block (chunk, bucket): LDS fp32 accum for 512 dst nodes x 16 dims (stride 17
// breaks the x16 bank pattern -> ~2-way aliasing, free). Gathers hit the
// 3.2 MB L2-resident chunk region. Chunk-major grid order time-aligns chunks.
__launch_bounds__(256, 4)
__global__ void agg_push(const uint16_t* __restrict__ feat, const uint32_t* __restrict__ bkt,
                         const int* __restrict__ gcur, uint16_t* __restrict__ outf) {
    __shared__ float acc[512 * 17];               // 34.8 KB
    const int chunk = blockIdx.x / NBUCK;
    const int b     = blockIdx.x % NBUCK;
    const int tid   = threadIdx.x;
    for (int i = tid; i < 512 * 17; i += 256) acc[i] = 0.f;
    __syncthreads();

    int n = gcur[b]; n = n > BCAP ? BCAP : n;
    const uint32_t* eb  = bkt + size_t(b) * BCAP;
    const uint16_t* reg = feat + size_t(chunk) * CHN;
    for (int i = tid; i < n; i += 256) {
        uint32_t e = eb[i];
        int dstl = (int)(e & 511u);
        int s    = (int)(e >> 9);
        const uint16_t* sp = reg + size_t(s) * 16;
        uint4 w0 = *reinterpret_cast<const uint4*>(sp);
        uint4 w1 = *reinterpret_cast<const uint4*>(sp + 8);
        float v[16];
        unpack16(w0, w1, v);
        float* ap = acc + dstl * 17;
        #pragma unroll
        for (int d = 0; d < 16; ++d) atomicAdd(&ap[d], v[d]);
    }
    __syncthreads();

    const int node0 = b * 512;
    uint16_t* oreg = outf + size_t(chunk) * CHN;
    for (int nl = tid; nl < 512; nl += 256) {
        int node = node0 + nl;
        if (node >= N_NODES) continue;
        const uint16_t* sp = reg + size_t(node) * 16;
        uint4 s0 = *reinterpret_cast<const uint4*>(sp);
        uint4 s1 = *reinterpret_cast<const uint4*>(sp + 8);
        float sv[16];
        unpack16(s0, s1, sv);
        const float* ap = acc + nl * 17;
        uint32_t o[8];
        #pragma unroll
        for (int j = 0; j < 8; ++j) {
            float a0 = ap[2*j] + sv[2*j];
            float a1 = ap[2*j+1] + sv[2*j+1];
            o[j] = (uint32_t)f32_to_bf16(a0) | ((uint32_t)f32_to_bf16(a1) << 16);
        }
        uint16_t* op = oreg + size_t(node) * 16;
        *reinterpret_cast<uint4*>(op)     = make_uint4(o[0], o[1], o[2], o[3]);
        *reinterpret_cast<uint4*>(op + 8) = make_uint4(o[4], o[5], o[6], o[7]);
    }
}

// ---- MFMA GEMM: out = act(A[M,K]bf16 @ W[K,128]bf16 + bias) -> bf16 --------
// A and out are CHUNK-MAJOR ([c][node][16]); WT is [n][k] row-major.
// A frag: m=lane&15, k=quad*8+j ; D frag: col=lane&15, row=quad*4+reg.
typedef __attribute__((ext_vector_type(8))) short short8;
typedef __attribute__((ext_vector_type(4))) float f32x4;

template <int K, bool RELU>
__launch_bounds__(256, 2)
__global__ void gemm_mfma(const uint16_t* __restrict__ A, const uint16_t* __restrict__ WT,
                          const float* __restrict__ bias, uint16_t* __restrict__ out,
                          int M) {
    constexpr int TSTR = 136;                       // +8 halfword pad
    __shared__ uint16_t tile[128 * TSTR];           // 34 KB
    const int tid  = threadIdx.x;
    const int wave = tid >> 6;
    const int lane = tid & 63;
    const int lr   = lane & 15;
    const int q    = lane >> 4;
    const int m_base = blockIdx.x * 128 + wave * 32;

    // A fragments from chunk-major layout: k = kb*32 + q*8 -> region kb*2+(q>>1)
    short8 afr[2][K / 32];
    #pragma unroll
    for (int mt = 0; mt < 2; ++mt) {
        int row = m_base + mt * 16 + lr;
        row = row < M ? row : (M - 1);
        #pragma unroll
        for (int kb = 0; kb < K / 32; ++kb) {
            const uint16_t* ap = A + size_t(kb * 2 + (q >> 1)) * CHN
                                   + size_t(row) * 16 + (q & 1) * 8;
            afr[mt][kb] = *reinterpret_cast<const short8*>(ap);
        }
    }

    const int trow = wave * 32 + q * 4;   // this lane's first tile row (local)
    for (int nt = 0; nt < 8; ++nt) {
        const uint16_t* bp = WT + size_t(nt * 16 + lr) * K + q * 8;
        f32x4 c0 = {0.f, 0.f, 0.f, 0.f};
        f32x4 c1 = {0.f, 0.f, 0.f, 0.f};
        #pragma unroll
        for (int kb = 0; kb < K / 32; ++kb) {
            short8 b = *reinterpret_cast<const short8*>(bp + kb * 32);
            c0 = __builtin_amdgcn_mfma_f32_16x16x32_bf16(afr[0][kb], b, c0, 0, 0, 0);
            c1 = __builtin_amdgcn_mfma_f32_16x16x32_bf16(afr[1][kb], b, c1, 0, 0, 0);
        }
        const float bv = bias[nt * 16 + lr];
        const int col = nt * 16 + lr;
        #pragma unroll
        for (int r = 0; r < 4; ++r) {
            float v0 = c0[r] + bv, v1 = c1[r] + bv;
            if (RELU) { v0 = fmaxf(v0, 0.f); v1 = fmaxf(v1, 0.f); }
            tile[(trow + r) * TSTR + col]      = f32_to_bf16(v0);
            tile[(trow + 16 + r) * TSTR + col] = f32_to_bf16(v1);
        }
    }
    __syncthreads();
    // chunk-major coalesced stores: 2048 16B pieces, 8 iterations
    #pragma unroll
    for (int it = 0; it < 8; ++it) {
        int p    = it * 256 + tid;
        int node = p & 127;
        int ch16 = p >> 7;            // 0..15
        int c    = ch16 >> 1, half = ch16 & 1;
        int grow = blockIdx.x * 128 + node;
        if (grow < M)
            *reinterpret_cast<uint4*>(out + size_t(c) * CHN + size_t(grow) * 16 + half * 8) =
                *reinterpret_cast<const uint4*>(&tile[node * TSTR + c * 16 + half * 8]);
    }
}

// ---- fused mean-pool + dot(Wc) + bc (h2 chunk-major) -----------------------
__global__ void pool_out(const uint16_t* __restrict__ h2, const int* __restrict__ goff,
                         const float* __restrict__ Wc, const float* __restrict__ bc,
                         float* __restrict__ out) {
    __shared__ float red[256];
    const int g    = blockIdx.x;
    const int tid  = threadIdx.x;
    const int d    = tid & 127;
    const int half = tid >> 7;
    const int c    = d >> 4, o = d & 15;
    const uint16_t* reg = h2 + size_t(c) * CHN + o;
    const int s = goff[g], e = goff[g + 1];
    float acc = 0.f;
    for (int n = s + half; n < e; n += 2)
        acc += bf16_to_f32(reg[size_t(n) * 16]);
    acc *= Wc[d];
    red[tid] = acc;
    __syncthreads();
    for (int off = 128; off > 0; off >>= 1) {
        if (tid < off) red[tid] += red[tid + off];
        __syncthreads();
    }
    if (tid == 0) {
        int c2 = e - s;
        float m = (c2 > 0) ? (red[0] / (float)c2) : 0.f;
        out[g] = m + bc[0];
    }
}

}  // namespace

extern "C" void kernel_launch(void* const* d_in, const int* in_sizes, int n_in,
                              void* d_out, int out_size, void* d_ws, size_t ws_size,
                              hipStream_t stream) {
    (void)in_sizes; (void)n_in; (void)out_size;
    if (ws_size < WS_NEED) return;

    const float* x   = (const float*)d_in[0];
    const void*  ei  = d_in[1];
    const void*  bat = d_in[2];
    const float* W1a = (const float*)d_in[3];
    const float* b1a = (const float*)d_in[4];
    const float* W1b = (const float*)d_in[5];
    const float* b1b = (const float*)d_in[6];
    const float* W2a = (const float*)d_in[7];
    const float* b2a = (const float*)d_in[8];
    const float* W2b = (const float*)d_in[9];
    const float* b2b = (const float*)d_in[10];
    const float* Wc  = (const float*)d_in[11];
    const float* bc  = (const float*)d_in[12];
    float* out = (float*)d_out;

    char* ws = (char*)d_ws;
    int*      goff = (int*)(ws + OFF_GOFF);
    int*      flg  = (int*)(ws + OFF_FLAG);
    int*      gcur = (int*)(ws + OFF_GCUR);
    uint32_t* bkt  = (uint32_t*)(ws + OFF_BKT);
    uint16_t* XC   = (uint16_t*)(ws + OFF_XC);
    uint16_t* T1a  = (uint16_t*)(ws + OFF_WT1A);
    uint16_t* T1b  = (uint16_t*)(ws + OFF_WT1B);
    uint16_t* T2a  = (uint16_t*)(ws + OFF_WT2A);
    uint16_t* T2b  = (uint16_t*)(ws + OFF_WT2B);
    uint16_t* F0   = (uint16_t*)(ws + OFF_F0);
    uint16_t* H1   = (uint16_t*)(ws + OFF_H1);
    uint16_t* H2   = (uint16_t*)(ws + OFF_H2);
    uint16_t* H3   = (uint16_t*)(ws + OFF_H3);

    hipMemsetAsync(flg, 0, 4, stream);
    hipMemsetAsync(gcur, 0, size_t(NBUCK) * 4, stream);

    detect_wide<<<1, 256, 0, stream>>>((const int*)ei, flg);
    bucket_edges<<<(N_EDGES + 4095) / 4096, 256, 0, stream>>>(ei, flg, gcur, bkt);
    goff_search<<<1, 576, 0, stream>>>(bat, flg, goff);
    cvt_x_chunk<<<(4 * N_NODES + 255) / 256, 256, 0, stream>>>(x, XC);
    cvt_weights<<<224, 256, 0, stream>>>(W1a, W1b, W2a, W2b, T1a, T1b, T2a, T2b);

    constexpr int GEMM_GRID = (N_NODES + 127) / 128;   // 782

    // conv1
    agg_push<<<NBUCK * 4, 256, 0, stream>>>(XC, bkt, gcur, F0);
    gemm_mfma<64, true><<<GEMM_GRID, 256, 0, stream>>>(F0, T1a, b1a, H1, N_NODES);
    gemm_mfma<128, true><<<GEMM_GRID, 256, 0, stream>>>(H1, T1b, b1b, H2, N_NODES);
    // conv2
    agg_push<<<NBUCK * 8, 256, 0, stream>>>(H2, bkt, gcur, H3);
    gemm_mfma<128, true><<<GEMM_GRID, 256, 0, stream>>>(H3, T2a, b2a, H1, N_NODES);
    gemm_mfma<128, true><<<GEMM_GRID, 256, 0, stream>>>(H1, T2b, b2b, H2, N_NODES);
    // pool + head
    pool_out<<<N_GRAPHS, 256, 0, stream>>>(H2, goff, Wc, bc, out);
}

// Round 5
// 446.239 us; speedup vs baseline: 4.6645x; 4.6645x over previous
//
#include <hip/hip_runtime.h>
#include <cstdint>
#include <cstddef>

// GIN 2-layer + mean-pool + head. bf16 features (row-major), fp32 accum.
// Edge build: bucketed two-phase counting sort -> per-node slot lists,
// then per-node SRC-SORT for gather locality. Each conv = one fused MLP
// kernel (GEMM1 -> LDS tile -> GEMM2) using MFMA bf16.

namespace {

constexpr int N_NODES  = 100000;
constexpr int N_EDGES  = 1600000;
constexpr int N_GRAPHS = 512;
constexpr int CAP      = 64;     // slots per node; Poisson(16) max over 100k ~ 42
constexpr int NBUCK    = (N_NODES + 511) / 512;   // 196 dst-range buckets
constexpr int BCAP     = 9216;   // per-bucket edge capacity (avg 8163, +11 sigma)
constexpr int SPLIT    = 4;      // blocks per bucket in scatter phase

constexpr size_t algn(size_t x){ return (x + size_t(255)) & ~size_t(255); }

constexpr size_t OFF_CNT   = 0;                                        // N ints
constexpr size_t OFF_GOFF  = algn(OFF_CNT   + size_t(N_NODES)*4);      // 513 ints
constexpr size_t OFF_FLAG  = algn(OFF_GOFF  + 513*4);                  // 1 int
constexpr size_t OFF_GCUR  = algn(OFF_FLAG  + 4);                      // NBUCK ints
constexpr size_t OFF_BKT   = algn(OFF_GCUR  + size_t(NBUCK)*4);        // NBUCK*BCAP int2
constexpr size_t OFF_SLOTS = algn(OFF_BKT   + size_t(NBUCK)*BCAP*8);   // N*CAP ints
constexpr size_t OFF_XB    = algn(OFF_SLOTS + size_t(N_NODES)*CAP*4);  // N*64 bf16
constexpr size_t OFF_WT1A  = algn(OFF_XB    + size_t(N_NODES)*64*2);   // 128*64 bf16
constexpr size_t OFF_WT1B  = algn(OFF_WT1A  + 8192*2);                 // 128*128 bf16
constexpr size_t OFF_WT2A  = algn(OFF_WT1B  + 16384*2);
constexpr size_t OFF_WT2B  = algn(OFF_WT2A  + 16384*2);
constexpr size_t OFF_F0    = algn(OFF_WT2B  + 16384*2);                // N*64 bf16
constexpr size_t OFF_H1    = algn(OFF_F0    + size_t(N_NODES)*64*2);   // N*128 bf16
constexpr size_t OFF_H2    = algn(OFF_H1    + size_t(N_NODES)*128*2);  // N*128 bf16
constexpr size_t WS_NEED   = OFF_H2 + size_t(N_NODES)*128*2;           // ~117 MB

// ---- helpers ---------------------------------------------------------------
__device__ __forceinline__ int load_idx(const void* p, size_t i, bool wide) {
    return wide ? (int)((const long long*)p)[i] : ((const int*)p)[i];
}

__device__ __forceinline__ uint16_t f32_to_bf16(float f) {
    union { float f; uint32_t i; } v; v.f = f;
    uint32_t u = v.i;
    uint32_t r = (u + 0x7FFFu + ((u >> 16) & 1u)) >> 16;   // RNE
    return (uint16_t)r;
}

__device__ __forceinline__ float bf16_to_f32(uint16_t h) {
    union { uint32_t i; float f; } v; v.i = ((uint32_t)h) << 16;
    return v.f;
}

__device__ __forceinline__ void unpack2(uint32_t u, float& a, float& b) {
    union { uint32_t i; float f; } x, y;
    x.i = u << 16;            // low half  = elem 0
    y.i = u & 0xFFFF0000u;    // high half = elem 1
    a = x.f; b = y.f;
}

__device__ __forceinline__ uint32_t pack2(float a, float b) {
    return (uint32_t)f32_to_bf16(a) | ((uint32_t)f32_to_bf16(b) << 16);
}

// ---- index width detection -------------------------------------------------
// int64 layout -> every odd 32-bit word (high half) is 0. flag==0 -> wide.
__global__ void detect_wide(const int* __restrict__ ei, int* __restrict__ flag) {
    int v = ei[2 * threadIdx.x + 1];
    if (v != 0) atomicOr(flag, 1);
}

// ---- phase A: partition edges into dst-range buckets -----------------------
__global__ void bucket_edges(const void* __restrict__ ei, const int* __restrict__ flag,
                             int* __restrict__ gcur, int2* __restrict__ bkt) {
    __shared__ int lcnt[NBUCK];
    __shared__ int lbase[NBUCK];
    const bool wide = (*flag == 0);
    const int tid = threadIdx.x;
    for (int i = tid; i < NBUCK; i += 256) lcnt[i] = 0;
    __syncthreads();
    int es[16], ed[16], er[16];
    const int base = blockIdx.x * 4096;
    #pragma unroll
    for (int i = 0; i < 16; ++i) {
        int e = base + i * 256 + tid;
        if (e < N_EDGES) {
            es[i] = load_idx(ei, size_t(e), wide);
            ed[i] = load_idx(ei, size_t(N_EDGES) + e, wide);
            er[i] = atomicAdd(&lcnt[ed[i] >> 9], 1);
        } else ed[i] = -1;
    }
    __syncthreads();
    for (int i = tid; i < NBUCK; i += 256)
        lbase[i] = atomicAdd(&gcur[i], lcnt[i]);
    __syncthreads();
    #pragma unroll
    for (int i = 0; i < 16; ++i) {
        if (ed[i] < 0) continue;
        int b = ed[i] >> 9;
        int idx = lbase[b] + er[i];
        if (idx < BCAP) bkt[size_t(b) * BCAP + idx] = make_int2(es[i], ed[i]);
    }
}

// ---- phase B: per-bucket scatter into slots (L2-resident regions) ----------
__global__ void scatter_slots(const int2* __restrict__ bkt, const int* __restrict__ gcur,
                              int* __restrict__ cnt, int* __restrict__ slots) {
    const int b    = blockIdx.x / SPLIT;
    const int part = blockIdx.x % SPLIT;
    int n = gcur[b]; n = n > BCAP ? BCAP : n;
    const int2* eb = bkt + size_t(b) * BCAP;
    for (int i = part * 256 + threadIdx.x; i < n; i += SPLIT * 256) {
        int2 e = eb[i];
        int p = atomicAdd(&cnt[e.y], 1);
        if (p < CAP) slots[size_t(e.y) * CAP + p] = e.x;
    }
}

// ---- per-node src-sort of slot lists (gather locality) ---------------------
// Lanes of the agg kernel walk slot index p in lockstep; sorted slots make the
// instantaneous gather working set a narrow moving band -> L2/L3 hits.
__launch_bounds__(128)
__global__ void sort_slots(const int* __restrict__ cnt, int* __restrict__ slots) {
    __shared__ int buf[128 * 65];          // stride 65 words: conflict-free
    const int tid  = threadIdx.x;
    const int node = blockIdx.x * 128 + tid;
    if (node >= N_NODES) return;
    int c = cnt[node]; c = c > CAP ? CAP : c;
    int* row = buf + tid * 65;
    int* gs  = slots + size_t(node) * CAP;
    for (int i = 0; i < c; ++i) row[i] = gs[i];
    for (int i = 1; i < c; ++i) {
        int key = row[i];
        int j = i - 1;
        while (j >= 0 && row[j] > key) { row[j + 1] = row[j]; --j; }
        row[j + 1] = key;
    }
    for (int i = 0; i < c; ++i) gs[i] = row[i];
}

// ---- graph offsets via binary search (batch is sorted) ---------------------
__global__ void goff_search(const void* __restrict__ bat, const int* __restrict__ flag,
                            int* __restrict__ goff) {
    int g = threadIdx.x;
    if (g > N_GRAPHS) return;
    const bool wide = (*flag == 0);
    int lo = 0, hi = N_NODES;
    while (lo < hi) {
        int mid = (lo + hi) >> 1;
        if (load_idx(bat, size_t(mid), wide) < g) lo = mid + 1; else hi = mid;
    }
    goff[g] = lo;
}

// ---- conversions -----------------------------------------------------------
__global__ void cvt_x_bf16(const float* __restrict__ x, uint16_t* __restrict__ xb) {
    size_t i = (size_t)(blockIdx.x * 256 + threadIdx.x) * 4;   // 6.4M floats
    float4 f = *reinterpret_cast<const float4*>(&x[i]);
    uint2 o = make_uint2(pack2(f.x, f.y), pack2(f.z, f.w));
    *reinterpret_cast<uint2*>(&xb[i]) = o;
}

// transpose W[K][128] fp32 -> WT[n*K + k] bf16 (four weights in one kernel)
__global__ void cvt_weights(const float* __restrict__ W1a, const float* __restrict__ W1b,
                            const float* __restrict__ W2a, const float* __restrict__ W2b,
                            uint16_t* __restrict__ T1a, uint16_t* __restrict__ T1b,
                            uint16_t* __restrict__ T2a, uint16_t* __restrict__ T2b) {
    int idx = blockIdx.x * 256 + threadIdx.x;    // 57344 total
    const float* W; uint16_t* T; int K; int local;
    if (idx < 8192)        { W = W1a; T = T1a; K = 64;  local = idx; }
    else if (idx < 24576)  { W = W1b; T = T1b; K = 128; local = idx - 8192; }
    else if (idx < 40960)  { W = W2a; T = T2a; K = 128; local = idx - 24576; }
    else                   { W = W2b; T = T2b; K = 128; local = idx - 40960; }
    int k = local >> 7, n = local & 127;
    T[n * K + k] = f32_to_bf16(W[local]);
}

// ---- aggregation: out[i] = x[i] + sum_{j->i} x[j]  (bf16 in/out, fp32 acc) -
template <int D>
__global__ void gin_aggregate(const uint16_t* __restrict__ xb, const int* __restrict__ cnt,
                              const int* __restrict__ slots, uint16_t* __restrict__ out) {
    constexpr int TPN = D / 8;                 // lanes per node (16B bf16 each)
    const int tid  = threadIdx.x;
    const int node = blockIdx.x * (256 / TPN) + tid / TPN;
    const int lane = tid % TPN;
    if (node >= N_NODES) return;
    const size_t rbase = size_t(node) * D + lane * 8;
    uint4 v = *reinterpret_cast<const uint4*>(&xb[rbase]);
    float a[8];
    unpack2(v.x, a[0], a[1]); unpack2(v.y, a[2], a[3]);
    unpack2(v.z, a[4], a[5]); unpack2(v.w, a[6], a[7]);
    int c = cnt[node]; c = c > CAP ? CAP : c;
    const int* sl = slots + size_t(node) * CAP;
    for (int p = 0; p < c; ++p) {
        int j = sl[p];
        uint4 w = *reinterpret_cast<const uint4*>(&xb[size_t(j) * D + lane * 8]);
        float b0, b1;
        unpack2(w.x, b0, b1); a[0] += b0; a[1] += b1;
        unpack2(w.y, b0, b1); a[2] += b0; a[3] += b1;
        unpack2(w.z, b0, b1); a[4] += b0; a[5] += b1;
        unpack2(w.w, b0, b1); a[6] += b0; a[7] += b1;
    }
    uint4 o = make_uint4(pack2(a[0], a[1]), pack2(a[2], a[3]),
                         pack2(a[4], a[5]), pack2(a[6], a[7]));
    *reinterpret_cast<uint4*>(&out[rbase]) = o;
}

// ---- fused conv MLP: out = relu( relu(A@Wa + ba) @ Wb + bb ) ---------------
// A[M,K1] bf16 row-major; Wa as WTa[n][k]; intermediate 128x128 bf16 tile
// lives in LDS between the two GEMMs; same tile reused to stage final stores.
// Frag maps (m89/m91-verified): A m=lane&15,k=quad*8+j ; D col=lane&15,
// row=quad*4+reg.
typedef __attribute__((ext_vector_type(8))) short short8;
typedef __attribute__((ext_vector_type(4))) float f32x4;

template <int K1>
__launch_bounds__(256, 3)
__global__ void gin_mlp(const uint16_t* __restrict__ A, const uint16_t* __restrict__ WTa,
                        const float* __restrict__ ba, const uint16_t* __restrict__ WTb,
                        const float* __restrict__ bb, uint16_t* __restrict__ out,
                        int M) {
    constexpr int TSTR = 136;                       // +8 halfword pad
    __shared__ uint16_t tile[128 * TSTR];           // 34 KB
    const int tid  = threadIdx.x;
    const int wave = tid >> 6;
    const int lane = tid & 63;
    const int lr   = lane & 15;
    const int q    = lane >> 4;
    const int m_base = blockIdx.x * 128 + wave * 32;
    const int trow   = wave * 32 + q * 4;           // first output row (local)

    // ---- GEMM1: A @ WTa -> tile (bias ba, relu) ----
    short8 afr1[2][K1 / 32];
    #pragma unroll
    for (int mt = 0; mt < 2; ++mt) {
        int row = m_base + mt * 16 + lr;
        row = row < M ? row : (M - 1);
        const uint16_t* ap = A + size_t(row) * K1 + q * 8;
        #pragma unroll
        for (int kb = 0; kb < K1 / 32; ++kb)
            afr1[mt][kb] = *reinterpret_cast<const short8*>(ap + kb * 32);
    }
    for (int nt = 0; nt < 8; ++nt) {
        const uint16_t* bp = WTa + size_t(nt * 16 + lr) * K1 + q * 8;
        f32x4 c0 = {0.f, 0.f, 0.f, 0.f};
        f32x4 c1 = {0.f, 0.f, 0.f, 0.f};
        #pragma unroll
        for (int kb = 0; kb < K1 / 32; ++kb) {
            short8 b = *reinterpret_cast<const short8*>(bp + kb * 32);
            c0 = __builtin_amdgcn_mfma_f32_16x16x32_bf16(afr1[0][kb], b, c0, 0, 0, 0);
            c1 = __builtin_amdgcn_mfma_f32_16x16x32_bf16(afr1[1][kb], b, c1, 0, 0, 0);
        }
        const float bv = ba[nt * 16 + lr];
        const int col = nt * 16 + lr;
        #pragma unroll
        for (int r = 0; r < 4; ++r) {
            float v0 = fmaxf(c0[r] + bv, 0.f);
            float v1 = fmaxf(c1[r] + bv, 0.f);
            tile[(trow + r) * TSTR + col]      = f32_to_bf16(v0);
            tile[(trow + 16 + r) * TSTR + col] = f32_to_bf16(v1);
        }
    }
    __syncthreads();

    // ---- A-fragments for GEMM2 from LDS tile ----
    short8 afr2[2][4];
    #pragma unroll
    for (int mt = 0; mt < 2; ++mt) {
        const int row = wave * 32 + mt * 16 + lr;
        #pragma unroll
        for (int kb = 0; kb < 4; ++kb)
            afr2[mt][kb] = *reinterpret_cast<const short8*>(
                &tile[row * TSTR + kb * 32 + q * 8]);
    }
    __syncthreads();   // tile will be overwritten by GEMM2 epilogue

    // ---- GEMM2: h1 @ WTb -> tile (bias bb, relu) ----
    for (int nt = 0; nt < 8; ++nt) {
        const uint16_t* bp = WTb + size_t(nt * 16 + lr) * 128 + q * 8;
        f32x4 c0 = {0.f, 0.f, 0.f, 0.f};
        f32x4 c1 = {0.f, 0.f, 0.f, 0.f};
        #pragma unroll
        for (int kb = 0; kb < 4; ++kb) {
            short8 b = *reinterpret_cast<const short8*>(bp + kb * 32);
            c0 = __builtin_amdgcn_mfma_f32_16x16x32_bf16(afr2[0][kb], b, c0, 0, 0, 0);
            c1 = __builtin_amdgcn_mfma_f32_16x16x32_bf16(afr2[1][kb], b, c1, 0, 0, 0);
        }
        const float bv = bb[nt * 16 + lr];
        const int col = nt * 16 + lr;
        #pragma unroll
        for (int r = 0; r < 4; ++r) {
            float v0 = fmaxf(c0[r] + bv, 0.f);
            float v1 = fmaxf(c1[r] + bv, 0.f);
            tile[(trow + r) * TSTR + col]      = f32_to_bf16(v0);
            tile[(trow + 16 + r) * TSTR + col] = f32_to_bf16(v1);
        }
    }
    __syncthreads();

    // ---- coalesced vectorized stores: 16 threads per row, 16B each ----
    const int c8 = (tid & 15) * 8;
    for (int rr = tid >> 4; rr < 128; rr += 16) {
        int grow = blockIdx.x * 128 + rr;
        if (grow < M)
            *reinterpret_cast<uint4*>(&out[size_t(grow) * 128 + c8]) =
                *reinterpret_cast<const uint4*>(&tile[rr * TSTR + c8]);
    }
}

// ---- fused mean-pool + dot(Wc) + bc ---------------------------------------
__global__ void pool_out(const uint16_t* __restrict__ h2, const int* __restrict__ goff,
                         const float* __restrict__ Wc, const float* __restrict__ bc,
                         float* __restrict__ out) {
    __shared__ float red[256];
    const int g    = blockIdx.x;
    const int tid  = threadIdx.x;
    const int d    = tid & 127;
    const int half = tid >> 7;
    const int s = goff[g], e = goff[g + 1];
    float acc = 0.f;
    for (int n = s + half; n < e; n += 2)
        acc += bf16_to_f32(h2[size_t(n) * 128 + d]);
    acc *= Wc[d];
    red[tid] = acc;
    __syncthreads();
    for (int off = 128; off > 0; off >>= 1) {
        if (tid < off) red[tid] += red[tid + off];
        __syncthreads();
    }
    if (tid == 0) {
        int c2 = e - s;
        float m = (c2 > 0) ? (red[0] / (float)c2) : 0.f;
        out[g] = m + bc[0];
    }
}

}  // namespace

extern "C" void kernel_launch(void* const* d_in, const int* in_sizes, int n_in,
                              void* d_out, int out_size, void* d_ws, size_t ws_size,
                              hipStream_t stream) {
    (void)in_sizes; (void)n_in; (void)out_size;
    if (ws_size < WS_NEED) return;

    const float* x   = (const float*)d_in[0];
    const void*  ei  = d_in[1];
    const void*  bat = d_in[2];
    const float* W1a = (const float*)d_in[3];
    const float* b1a = (const float*)d_in[4];
    const float* W1b = (const float*)d_in[5];
    const float* b1b = (const float*)d_in[6];
    const float* W2a = (const float*)d_in[7];
    const float* b2a = (const float*)d_in[8];
    const float* W2b = (const float*)d_in[9];
    const float* b2b = (const float*)d_in[10];
    const float* Wc  = (const float*)d_in[11];
    const float* bc  = (const float*)d_in[12];
    float* out = (float*)d_out;

    char* ws = (char*)d_ws;
    int*      cnt   = (int*)(ws + OFF_CNT);
    int*      goff  = (int*)(ws + OFF_GOFF);
    int*      flg   = (int*)(ws + OFF_FLAG);
    int*      gcur  = (int*)(ws + OFF_GCUR);
    int2*     bkt   = (int2*)(ws + OFF_BKT);
    int*      slots = (int*)(ws + OFF_SLOTS);
    uint16_t* xb    = (uint16_t*)(ws + OFF_XB);
    uint16_t* T1a   = (uint16_t*)(ws + OFF_WT1A);
    uint16_t* T1b   = (uint16_t*)(ws + OFF_WT1B);
    uint16_t* T2a   = (uint16_t*)(ws + OFF_WT2A);
    uint16_t* T2b   = (uint16_t*)(ws + OFF_WT2B);
    uint16_t* F0    = (uint16_t*)(ws + OFF_F0);
    uint16_t* H1    = (uint16_t*)(ws + OFF_H1);
    uint16_t* H2    = (uint16_t*)(ws + OFF_H2);

    hipMemsetAsync(cnt, 0, size_t(N_NODES) * 4, stream);
    hipMemsetAsync(flg, 0, 4, stream);
    hipMemsetAsync(gcur, 0, size_t(NBUCK) * 4, stream);

    detect_wide<<<1, 256, 0, stream>>>((const int*)ei, flg);

    // edge build: bucket -> scatter -> per-node src sort
    bucket_edges<<<(N_EDGES + 4095) / 4096, 256, 0, stream>>>(ei, flg, gcur, bkt);
    scatter_slots<<<NBUCK * SPLIT, 256, 0, stream>>>(bkt, gcur, cnt, slots);
    sort_slots<<<(N_NODES + 127) / 128, 128, 0, stream>>>(cnt, slots);
    goff_search<<<1, 576, 0, stream>>>(bat, flg, goff);
    cvt_x_bf16<<<(N_NODES * 64 / 4 + 255) / 256, 256, 0, stream>>>(x, xb);
    cvt_weights<<<224, 256, 0, stream>>>(W1a, W1b, W2a, W2b, T1a, T1b, T2a, T2b);

    constexpr int GEMM_GRID = (N_NODES + 127) / 128;   // 782

    // conv1
    gin_aggregate<64><<<(N_NODES + 31) / 32, 256, 0, stream>>>(xb, cnt, slots, F0);
    gin_mlp<64><<<GEMM_GRID, 256, 0, stream>>>(F0, T1a, b1a, T1b, b1b, H1, N_NODES);
    // conv2
    gin_aggregate<128><<<(N_NODES + 15) / 16, 256, 0, stream>>>(H1, cnt, slots, H2);
    gin_mlp<128><<<GEMM_GRID, 256, 0, stream>>>(H2, T2a, b2a, T2b, b2b, H1, N_NODES);
    // pool + head
    pool_out<<<N_GRAPHS, 256, 0, stream>>>(H1, goff, Wc, bc, out);
}

// Round 6
// 371.891 us; speedup vs baseline: 5.5971x; 1.1999x over previous
//
#include <hip/hip_runtime.h>
#include <cstdint>
#include <cstddef>

// GIN 2-layer + mean-pool + head. bf16 features (row-major), fp32 accum.
// Edge build: bucket (dst>>9) -> per-bucket LDS counting sort -> dense
// dst-sorted CSR (no global atomics, no slot scatter). Each conv = one
// fused MLP kernel (GEMM1 -> LDS tile -> GEMM2) using MFMA bf16.

namespace {

constexpr int N_NODES  = 100000;
constexpr int N_EDGES  = 1600000;
constexpr int N_GRAPHS = 512;
constexpr int NBUCK    = (N_NODES + 511) / 512;   // 196 dst-range buckets
constexpr int BCAP     = 9216;   // per-bucket edge capacity (avg 8163, +11 sigma)

constexpr size_t algn(size_t x){ return (x + size_t(255)) & ~size_t(255); }

constexpr size_t OFF_CNT   = 0;                                        // N ints
constexpr size_t OFF_ROW   = algn(OFF_CNT   + size_t(N_NODES)*4);      // N ints
constexpr size_t OFF_GOFF  = algn(OFF_ROW   + size_t(N_NODES)*4);      // 513 ints
constexpr size_t OFF_FLAG  = algn(OFF_GOFF  + 513*4);                  // 1 int
constexpr size_t OFF_GCUR  = algn(OFF_FLAG  + 4);                      // NBUCK ints
constexpr size_t OFF_BKT   = algn(OFF_GCUR  + size_t(NBUCK)*4);        // NBUCK*BCAP u32
constexpr size_t OFF_CSR   = algn(OFF_BKT   + size_t(NBUCK)*BCAP*4);   // NBUCK*BCAP u32
constexpr size_t OFF_XB    = algn(OFF_CSR   + size_t(NBUCK)*BCAP*4);   // N*64 bf16
constexpr size_t OFF_WT1A  = algn(OFF_XB    + size_t(N_NODES)*64*2);   // 128*64 bf16
constexpr size_t OFF_WT1B  = algn(OFF_WT1A  + 8192*2);                 // 128*128 bf16
constexpr size_t OFF_WT2A  = algn(OFF_WT1B  + 16384*2);
constexpr size_t OFF_WT2B  = algn(OFF_WT2A  + 16384*2);
constexpr size_t OFF_F0    = algn(OFF_WT2B  + 16384*2);                // N*64 bf16
constexpr size_t OFF_H1    = algn(OFF_F0    + size_t(N_NODES)*64*2);   // N*128 bf16
constexpr size_t OFF_H2    = algn(OFF_H1    + size_t(N_NODES)*128*2);  // N*128 bf16
constexpr size_t WS_NEED   = OFF_H2 + size_t(N_NODES)*128*2;           // ~105 MB

// ---- helpers ---------------------------------------------------------------
__device__ __forceinline__ int load_idx(const void* p, size_t i, bool wide) {
    return wide ? (int)((const long long*)p)[i] : ((const int*)p)[i];
}

__device__ __forceinline__ uint16_t f32_to_bf16(float f) {
    union { float f; uint32_t i; } v; v.f = f;
    uint32_t u = v.i;
    uint32_t r = (u + 0x7FFFu + ((u >> 16) & 1u)) >> 16;   // RNE
    return (uint16_t)r;
}

__device__ __forceinline__ float bf16_to_f32(uint16_t h) {
    union { uint32_t i; float f; } v; v.i = ((uint32_t)h) << 16;
    return v.f;
}

__device__ __forceinline__ void unpack2(uint32_t u, float& a, float& b) {
    union { uint32_t i; float f; } x, y;
    x.i = u << 16;            // low half  = elem 0
    y.i = u & 0xFFFF0000u;    // high half = elem 1
    a = x.f; b = y.f;
}

__device__ __forceinline__ uint32_t pack2(float a, float b) {
    return (uint32_t)f32_to_bf16(a) | ((uint32_t)f32_to_bf16(b) << 16);
}

// ---- index width detection -------------------------------------------------
// int64 layout -> every odd 32-bit word (high half) is 0. flag==0 -> wide.
__global__ void detect_wide(const int* __restrict__ ei, int* __restrict__ flag) {
    int v = ei[2 * threadIdx.x + 1];
    if (v != 0) atomicOr(flag, 1);
}

// ---- phase A: partition edges into dst-range buckets, packed src<<9|dstl ---
__global__ void bucket_edges(const void* __restrict__ ei, const int* __restrict__ flag,
                             int* __restrict__ gcur, uint32_t* __restrict__ bkt) {
    __shared__ int lcnt[NBUCK];
    __shared__ int lbase[NBUCK];
    const bool wide = (*flag == 0);
    const int tid = threadIdx.x;
    for (int i = tid; i < NBUCK; i += 256) lcnt[i] = 0;
    __syncthreads();
    int es[16], ed[16], er[16];
    const int base = blockIdx.x * 4096;
    #pragma unroll
    for (int i = 0; i < 16; ++i) {
        int e = base + i * 256 + tid;
        if (e < N_EDGES) {
            es[i] = load_idx(ei, size_t(e), wide);
            ed[i] = load_idx(ei, size_t(N_EDGES) + e, wide);
            er[i] = atomicAdd(&lcnt[ed[i] >> 9], 1);
        } else ed[i] = -1;
    }
    __syncthreads();
    for (int i = tid; i < NBUCK; i += 256)
        lbase[i] = atomicAdd(&gcur[i], lcnt[i]);
    __syncthreads();
    #pragma unroll
    for (int i = 0; i < 16; ++i) {
        if (ed[i] < 0) continue;
        int b = ed[i] >> 9;
        int idx = lbase[b] + er[i];
        if (idx < BCAP)
            bkt[size_t(b) * BCAP + idx] = ((uint32_t)es[i] << 9) | (uint32_t)(ed[i] & 511);
    }
}

// ---- phase B: per-bucket LDS counting sort -> dense dst-sorted CSR ---------
// One block per bucket. Histogram (512 LDS counters) -> LDS scan -> placement.
// Outputs: csr[b*BCAP + ...] = src indices grouped by dst; row[node] = segment
// start; cnt[node] = degree. All writes contiguous / L2-resident.
__launch_bounds__(256)
__global__ void sort_bucket(const uint32_t* __restrict__ bkt, const int* __restrict__ gcur,
                            uint32_t* __restrict__ csr, int* __restrict__ row,
                            int* __restrict__ cnt) {
    __shared__ int h[512];
    __shared__ int cur[512];
    __shared__ int sd[256];
    const int b = blockIdx.x, tid = threadIdx.x;
    int n = gcur[b]; n = n > BCAP ? BCAP : n;
    const uint32_t* eb = bkt + size_t(b) * BCAP;
    h[tid] = 0; h[tid + 256] = 0;
    __syncthreads();
    for (int i = tid; i < n; i += 256) atomicAdd(&h[eb[i] & 511u], 1);
    __syncthreads();
    const int a0 = h[2 * tid], a1 = h[2 * tid + 1];
    int s = a0 + a1;
    sd[tid] = s;
    __syncthreads();
    for (int off = 1; off < 256; off <<= 1) {
        int t = (tid >= off) ? sd[tid - off] : 0;
        __syncthreads();
        sd[tid] += t;
        __syncthreads();
    }
    const int base = sd[tid] - s;      // exclusive prefix over thread's 2 bins
    cur[2 * tid]     = base;
    cur[2 * tid + 1] = base + a0;
    const int node0 = b * 512;
    if (node0 + 2 * tid < N_NODES) {
        row[node0 + 2 * tid] = b * BCAP + base;
        cnt[node0 + 2 * tid] = a0;
    }
    if (node0 + 2 * tid + 1 < N_NODES) {
        row[node0 + 2 * tid + 1] = b * BCAP + base + a0;
        cnt[node0 + 2 * tid + 1] = a1;
    }
    __syncthreads();
    uint32_t* cb = csr + size_t(b) * BCAP;
    for (int i = tid; i < n; i += 256) {
        uint32_t e = eb[i];
        int p = atomicAdd(&cur[e & 511u], 1);
        cb[p] = e >> 9;
    }
}

// ---- graph offsets via binary search (batch is sorted) ---------------------
__global__ void goff_search(const void* __restrict__ bat, const int* __restrict__ flag,
                            int* __restrict__ goff) {
    int g = threadIdx.x;
    if (g > N_GRAPHS) return;
    const bool wide = (*flag == 0);
    int lo = 0, hi = N_NODES;
    while (lo < hi) {
        int mid = (lo + hi) >> 1;
        if (load_idx(bat, size_t(mid), wide) < g) lo = mid + 1; else hi = mid;
    }
    goff[g] = lo;
}

// ---- conversions -----------------------------------------------------------
__global__ void cvt_x_bf16(const float* __restrict__ x, uint16_t* __restrict__ xb) {
    size_t i = (size_t)(blockIdx.x * 256 + threadIdx.x) * 4;   // 6.4M floats
    float4 f = *reinterpret_cast<const float4*>(&x[i]);
    uint2 o = make_uint2(pack2(f.x, f.y), pack2(f.z, f.w));
    *reinterpret_cast<uint2*>(&xb[i]) = o;
}

// transpose W[K][128] fp32 -> WT[n*K + k] bf16 (four weights in one kernel)
__global__ void cvt_weights(const float* __restrict__ W1a, const float* __restrict__ W1b,
                            const float* __restrict__ W2a, const float* __restrict__ W2b,
                            uint16_t* __restrict__ T1a, uint16_t* __restrict__ T1b,
                            uint16_t* __restrict__ T2a, uint16_t* __restrict__ T2b) {
    int idx = blockIdx.x * 256 + threadIdx.x;    // 57344 total
    const float* W; uint16_t* T; int K; int local;
    if (idx < 8192)        { W = W1a; T = T1a; K = 64;  local = idx; }
    else if (idx < 24576)  { W = W1b; T = T1b; K = 128; local = idx - 8192; }
    else if (idx < 40960)  { W = W2a; T = T2a; K = 128; local = idx - 24576; }
    else                   { W = W2b; T = T2b; K = 128; local = idx - 40960; }
    int k = local >> 7, n = local & 127;
    T[n * K + k] = f32_to_bf16(W[local]);
}

// ---- aggregation: out[i] = x[i] + sum_{j->i} x[j]  (bf16 in/out, fp32 acc) -
template <int D>
__global__ void gin_aggregate(const uint16_t* __restrict__ xb, const int* __restrict__ row,
                              const int* __restrict__ cnt, const uint32_t* __restrict__ csr,
                              uint16_t* __restrict__ out) {
    constexpr int TPN = D / 8;                 // lanes per node (16B bf16 each)
    const int tid  = threadIdx.x;
    const int node = blockIdx.x * (256 / TPN) + tid / TPN;
    const int lane = tid % TPN;
    if (node >= N_NODES) return;
    const size_t rbase = size_t(node) * D + lane * 8;
    uint4 v = *reinterpret_cast<const uint4*>(&xb[rbase]);
    float a[8];
    unpack2(v.x, a[0], a[1]); unpack2(v.y, a[2], a[3]);
    unpack2(v.z, a[4], a[5]); unpack2(v.w, a[6], a[7]);
    const int c = cnt[node];
    const uint32_t* sl = csr + row[node];
    for (int p = 0; p < c; ++p) {
        int j = (int)sl[p];
        uint4 w = *reinterpret_cast<const uint4*>(&xb[size_t(j) * D + lane * 8]);
        float b0, b1;
        unpack2(w.x, b0, b1); a[0] += b0; a[1] += b1;
        unpack2(w.y, b0, b1); a[2] += b0; a[3] += b1;
        unpack2(w.z, b0, b1); a[4] += b0; a[5] += b1;
        unpack2(w.w, b0, b1); a[6] += b0; a[7] += b1;
    }
    uint4 o = make_uint4(pack2(a[0], a[1]), pack2(a[2], a[3]),
                         pack2(a[4], a[5]), pack2(a[6], a[7]));
    *reinterpret_cast<uint4*>(&out[rbase]) = o;
}

// ---- fused conv MLP: out = relu( relu(A@Wa + ba) @ Wb + bb ) ---------------
// A[M,K1] bf16 row-major; Wa as WTa[n][k]; intermediate 128x128 bf16 tile
// lives in LDS between the two GEMMs; same tile reused to stage final stores.
// Frag maps (m89/m91-verified): A m=lane&15,k=quad*8+j ; D col=lane&15,
// row=quad*4+reg.
typedef __attribute__((ext_vector_type(8))) short short8;
typedef __attribute__((ext_vector_type(4))) float f32x4;

template <int K1>
__launch_bounds__(256, 3)
__global__ void gin_mlp(const uint16_t* __restrict__ A, const uint16_t* __restrict__ WTa,
                        const float* __restrict__ ba, const uint16_t* __restrict__ WTb,
                        const float* __restrict__ bb, uint16_t* __restrict__ out,
                        int M) {
    constexpr int TSTR = 136;                       // +8 halfword pad
    __shared__ uint16_t tile[128 * TSTR];           // 34 KB
    const int tid  = threadIdx.x;
    const int wave = tid >> 6;
    const int lane = tid & 63;
    const int lr   = lane & 15;
    const int q    = lane >> 4;
    const int m_base = blockIdx.x * 128 + wave * 32;
    const int trow   = wave * 32 + q * 4;           // first output row (local)

    // ---- GEMM1: A @ WTa -> tile (bias ba, relu) ----
    short8 afr1[2][K1 / 32];
    #pragma unroll
    for (int mt = 0; mt < 2; ++mt) {
        int row = m_base + mt * 16 + lr;
        row = row < M ? row : (M - 1);
        const uint16_t* ap = A + size_t(row) * K1 + q * 8;
        #pragma unroll
        for (int kb = 0; kb < K1 / 32; ++kb)
            afr1[mt][kb] = *reinterpret_cast<const short8*>(ap + kb * 32);
    }
    for (int nt = 0; nt < 8; ++nt) {
        const uint16_t* bp = WTa + size_t(nt * 16 + lr) * K1 + q * 8;
        f32x4 c0 = {0.f, 0.f, 0.f, 0.f};
        f32x4 c1 = {0.f, 0.f, 0.f, 0.f};
        #pragma unroll
        for (int kb = 0; kb < K1 / 32; ++kb) {
            short8 b = *reinterpret_cast<const short8*>(bp + kb * 32);
            c0 = __builtin_amdgcn_mfma_f32_16x16x32_bf16(afr1[0][kb], b, c0, 0, 0, 0);
            c1 = __builtin_amdgcn_mfma_f32_16x16x32_bf16(afr1[1][kb], b, c1, 0, 0, 0);
        }
        const float bv = ba[nt * 16 + lr];
        const int col = nt * 16 + lr;
        #pragma unroll
        for (int r = 0; r < 4; ++r) {
            float v0 = fmaxf(c0[r] + bv, 0.f);
            float v1 = fmaxf(c1[r] + bv, 0.f);
            tile[(trow + r) * TSTR + col]      = f32_to_bf16(v0);
            tile[(trow + 16 + r) * TSTR + col] = f32_to_bf16(v1);
        }
    }
    __syncthreads();

    // ---- A-fragments for GEMM2 from LDS tile ----
    short8 afr2[2][4];
    #pragma unroll
    for (int mt = 0; mt < 2; ++mt) {
        const int row = wave * 32 + mt * 16 + lr;
        #pragma unroll
        for (int kb = 0; kb < 4; ++kb)
            afr2[mt][kb] = *reinterpret_cast<const short8*>(
                &tile[row * TSTR + kb * 32 + q * 8]);
    }
    __syncthreads();   // tile will be overwritten by GEMM2 epilogue

    // ---- GEMM2: h1 @ WTb -> tile (bias bb, relu) ----
    for (int nt = 0; nt < 8; ++nt) {
        const uint16_t* bp = WTb + size_t(nt * 16 + lr) * 128 + q * 8;
        f32x4 c0 = {0.f, 0.f, 0.f, 0.f};
        f32x4 c1 = {0.f, 0.f, 0.f, 0.f};
        #pragma unroll
        for (int kb = 0; kb < 4; ++kb) {
            short8 b = *reinterpret_cast<const short8*>(bp + kb * 32);
            c0 = __builtin_amdgcn_mfma_f32_16x16x32_bf16(afr2[0][kb], b, c0, 0, 0, 0);
            c1 = __builtin_amdgcn_mfma_f32_16x16x32_bf16(afr2[1][kb], b, c1, 0, 0, 0);
        }
        const float bv = bb[nt * 16 + lr];
        const int col = nt * 16 + lr;
        #pragma unroll
        for (int r = 0; r < 4; ++r) {
            float v0 = fmaxf(c0[r] + bv, 0.f);
            float v1 = fmaxf(c1[r] + bv, 0.f);
            tile[(trow + r) * TSTR + col]      = f32_to_bf16(v0);
            tile[(trow + 16 + r) * TSTR + col] = f32_to_bf16(v1);
        }
    }
    __syncthreads();

    // ---- coalesced vectorized stores: 16 threads per row, 16B each ----
    const int c8 = (tid & 15) * 8;
    for (int rr = tid >> 4; rr < 128; rr += 16) {
        int grow = blockIdx.x * 128 + rr;
        if (grow < M)
            *reinterpret_cast<uint4*>(&out[size_t(grow) * 128 + c8]) =
                *reinterpret_cast<const uint4*>(&tile[rr * TSTR + c8]);
    }
}

// ---- fused mean-pool + dot(Wc) + bc ---------------------------------------
__global__ void pool_out(const uint16_t* __restrict__ h2, const int* __restrict__ goff,
                         const float* __restrict__ Wc, const float* __restrict__ bc,
                         float* __restrict__ out) {
    __shared__ float red[256];
    const int g    = blockIdx.x;
    const int tid  = threadIdx.x;
    const int d    = tid & 127;
    const int half = tid >> 7;
    const int s = goff[g], e = goff[g + 1];
    float acc = 0.f;
    for (int n = s + half; n < e; n += 2)
        acc += bf16_to_f32(h2[size_t(n) * 128 + d]);
    acc *= Wc[d];
    red[tid] = acc;
    __syncthreads();
    for (int off = 128; off > 0; off >>= 1) {
        if (tid < off) red[tid] += red[tid + off];
        __syncthreads();
    }
    if (tid == 0) {
        int c2 = e - s;
        float m = (c2 > 0) ? (red[0] / (float)c2) : 0.f;
        out[g] = m + bc[0];
    }
}

}  // namespace

extern "C" void kernel_launch(void* const* d_in, const int* in_sizes, int n_in,
                              void* d_out, int out_size, void* d_ws, size_t ws_size,
                              hipStream_t stream) {
    (void)in_sizes; (void)n_in; (void)out_size;
    if (ws_size < WS_NEED) return;

    const float* x   = (const float*)d_in[0];
    const void*  ei  = d_in[1];
    const void*  bat = d_in[2];
    const float* W1a = (const float*)d_in[3];
    const float* b1a = (const float*)d_in[4];
    const float* W1b = (const float*)d_in[5];
    const float* b1b = (const float*)d_in[6];
    const float* W2a = (const float*)d_in[7];
    const float* b2a = (const float*)d_in[8];
    const float* W2b = (const float*)d_in[9];
    const float* b2b = (const float*)d_in[10];
    const float* Wc  = (const float*)d_in[11];
    const float* bc  = (const float*)d_in[12];
    float* out = (float*)d_out;

    char* ws = (char*)d_ws;
    int*      cnt  = (int*)(ws + OFF_CNT);
    int*      row  = (int*)(ws + OFF_ROW);
    int*      goff = (int*)(ws + OFF_GOFF);
    int*      flg  = (int*)(ws + OFF_FLAG);
    int*      gcur = (int*)(ws + OFF_GCUR);
    uint32_t* bkt  = (uint32_t*)(ws + OFF_BKT);
    uint32_t* csr  = (uint32_t*)(ws + OFF_CSR);
    uint16_t* xb   = (uint16_t*)(ws + OFF_XB);
    uint16_t* T1a  = (uint16_t*)(ws + OFF_WT1A);
    uint16_t* T1b  = (uint16_t*)(ws + OFF_WT1B);
    uint16_t* T2a  = (uint16_t*)(ws + OFF_WT2A);
    uint16_t* T2b  = (uint16_t*)(ws + OFF_WT2B);
    uint16_t* F0   = (uint16_t*)(ws + OFF_F0);
    uint16_t* H1   = (uint16_t*)(ws + OFF_H1);
    uint16_t* H2   = (uint16_t*)(ws + OFF_H2);

    hipMemsetAsync(flg, 0, 4, stream);
    hipMemsetAsync(gcur, 0, size_t(NBUCK) * 4, stream);

    detect_wide<<<1, 256, 0, stream>>>((const int*)ei, flg);

    // edge build: bucket -> per-bucket LDS counting sort -> dense CSR
    bucket_edges<<<(N_EDGES + 4095) / 4096, 256, 0, stream>>>(ei, flg, gcur, bkt);
    sort_bucket<<<NBUCK, 256, 0, stream>>>(bkt, gcur, csr, row, cnt);
    goff_search<<<1, 576, 0, stream>>>(bat, flg, goff);
    cvt_x_bf16<<<(N_NODES * 64 / 4 + 255) / 256, 256, 0, stream>>>(x, xb);
    cvt_weights<<<224, 256, 0, stream>>>(W1a, W1b, W2a, W2b, T1a, T1b, T2a, T2b);

    constexpr int GEMM_GRID = (N_NODES + 127) / 128;   // 782

    // conv1
    gin_aggregate<64><<<(N_NODES + 31) / 32, 256, 0, stream>>>(xb, row, cnt, csr, F0);
    gin_mlp<64><<<GEMM_GRID, 256, 0, stream>>>(F0, T1a, b1a, T1b, b1b, H1, N_NODES);
    // conv2
    gin_aggregate<128><<<(N_NODES + 15) / 16, 256, 0, stream>>>(H1, row, cnt, csr, H2);
    gin_mlp<128><<<GEMM_GRID, 256, 0, stream>>>(H2, T2a, b2a, T2b, b2b, H1, N_NODES);
    // pool + head
    pool_out<<<N_GRAPHS, 256, 0, stream>>>(H1, goff, Wc, bc, out);
}

// Round 7
// 334.677 us; speedup vs baseline: 6.2194x; 1.1112x over previous
//
#include <hip/hip_runtime.h>
#include <cstdint>
#include <cstddef>

// GIN 2-layer + mean-pool + head. bf16 features (row-major), fp32 accum.
// Edge build: bucket (dst>>9) -> per-bucket LDS counting sort -> dense CSR.
// Prep work (bucket + converts + graph offsets) fused into one kernel.
// Aggregation: gather with x4-unrolled loads (memory-level parallelism).
// Each conv MLP = one fused kernel (GEMM1 -> LDS tile -> GEMM2), MFMA bf16.

namespace {

constexpr int N_NODES  = 100000;
constexpr int N_EDGES  = 1600000;
constexpr int N_GRAPHS = 512;
constexpr int NBUCK    = (N_NODES + 511) / 512;   // 196 dst-range buckets
constexpr int BCAP     = 9216;   // per-bucket edge capacity (avg 8163, +11 sigma)

constexpr size_t algn(size_t x){ return (x + size_t(255)) & ~size_t(255); }

constexpr size_t OFF_CNT   = 0;                                        // N ints
constexpr size_t OFF_ROW   = algn(OFF_CNT   + size_t(N_NODES)*4);      // N ints
constexpr size_t OFF_GOFF  = algn(OFF_ROW   + size_t(N_NODES)*4);      // 513 ints
constexpr size_t OFF_FLAG  = algn(OFF_GOFF  + 513*4);                  // 1 int
constexpr size_t OFF_GCUR  = algn(OFF_FLAG  + 4);                      // NBUCK ints
constexpr size_t OFF_BKT   = algn(OFF_GCUR  + size_t(NBUCK)*4);        // NBUCK*BCAP u32
constexpr size_t OFF_CSR   = algn(OFF_BKT   + size_t(NBUCK)*BCAP*4);   // NBUCK*BCAP u32
constexpr size_t OFF_XB    = algn(OFF_CSR   + size_t(NBUCK)*BCAP*4);   // N*64 bf16
constexpr size_t OFF_WT1A  = algn(OFF_XB    + size_t(N_NODES)*64*2);   // 128*64 bf16
constexpr size_t OFF_WT1B  = algn(OFF_WT1A  + 8192*2);                 // 128*128 bf16
constexpr size_t OFF_WT2A  = algn(OFF_WT1B  + 16384*2);
constexpr size_t OFF_WT2B  = algn(OFF_WT2A  + 16384*2);
constexpr size_t OFF_F0    = algn(OFF_WT2B  + 16384*2);                // N*64 bf16
constexpr size_t OFF_H1    = algn(OFF_F0    + size_t(N_NODES)*64*2);   // N*128 bf16
constexpr size_t OFF_H2    = algn(OFF_H1    + size_t(N_NODES)*128*2);  // N*128 bf16
constexpr size_t WS_NEED   = OFF_H2 + size_t(N_NODES)*128*2;           // ~105 MB

// prep-kernel block partition (bucket blocks first: their LDS-atomic latency
// overlaps the streaming converts)
constexpr int PB_BUCKET = (N_EDGES + 4095) / 4096;          // 391
constexpr int PB_CVTX   = (N_NODES * 64 / 4 + 255) / 256;   // 6250
constexpr int PB_CVTW   = 224;
constexpr int PB_TOTAL  = PB_BUCKET + PB_CVTX + PB_CVTW + 1;

// ---- helpers ---------------------------------------------------------------
__device__ __forceinline__ int load_idx(const void* p, size_t i, bool wide) {
    return wide ? (int)((const long long*)p)[i] : ((const int*)p)[i];
}

__device__ __forceinline__ uint16_t f32_to_bf16(float f) {
    union { float f; uint32_t i; } v; v.f = f;
    uint32_t u = v.i;
    uint32_t r = (u + 0x7FFFu + ((u >> 16) & 1u)) >> 16;   // RNE
    return (uint16_t)r;
}

__device__ __forceinline__ float bf16_to_f32(uint16_t h) {
    union { uint32_t i; float f; } v; v.i = ((uint32_t)h) << 16;
    return v.f;
}

__device__ __forceinline__ void unpack2(uint32_t u, float& a, float& b) {
    union { uint32_t i; float f; } x, y;
    x.i = u << 16;            // low half  = elem 0
    y.i = u & 0xFFFF0000u;    // high half = elem 1
    a = x.f; b = y.f;
}

__device__ __forceinline__ uint32_t pack2(float a, float b) {
    return (uint32_t)f32_to_bf16(a) | ((uint32_t)f32_to_bf16(b) << 16);
}

__device__ __forceinline__ void accum8(float* a, uint4 w) {
    float b0, b1;
    unpack2(w.x, b0, b1); a[0] += b0; a[1] += b1;
    unpack2(w.y, b0, b1); a[2] += b0; a[3] += b1;
    unpack2(w.z, b0, b1); a[4] += b0; a[5] += b1;
    unpack2(w.w, b0, b1); a[6] += b0; a[7] += b1;
}

// ---- index width detection -------------------------------------------------
// int64 layout -> every odd 32-bit word (high half) is 0. flag==0 -> wide.
__global__ void detect_wide(const int* __restrict__ ei, int* __restrict__ flag) {
    int v = ei[2 * threadIdx.x + 1];
    if (v != 0) atomicOr(flag, 1);
}

// ---- fused prep: bucket_edges | cvt_x | cvt_weights | goff_search ----------
__global__ void prep(const void* __restrict__ ei, const void* __restrict__ bat,
                     const int* __restrict__ flag,
                     const float* __restrict__ x,
                     const float* __restrict__ W1a, const float* __restrict__ W1b,
                     const float* __restrict__ W2a, const float* __restrict__ W2b,
                     int* __restrict__ gcur, uint32_t* __restrict__ bkt,
                     uint16_t* __restrict__ xb,
                     uint16_t* __restrict__ T1a, uint16_t* __restrict__ T1b,
                     uint16_t* __restrict__ T2a, uint16_t* __restrict__ T2b,
                     int* __restrict__ goff) {
    __shared__ int lcnt[NBUCK];
    __shared__ int lbase[NBUCK];
    const int bx  = blockIdx.x;
    const int tid = threadIdx.x;
    const bool wide = (*flag == 0);

    if (bx < PB_BUCKET) {
        // ---- partition edges into dst-range buckets, packed src<<9|dstl ----
        for (int i = tid; i < NBUCK; i += 256) lcnt[i] = 0;
        __syncthreads();
        int es[16], ed[16], er[16];
        const int base = bx * 4096;
        #pragma unroll
        for (int i = 0; i < 16; ++i) {
            int e = base + i * 256 + tid;
            if (e < N_EDGES) {
                es[i] = load_idx(ei, size_t(e), wide);
                ed[i] = load_idx(ei, size_t(N_EDGES) + e, wide);
                er[i] = atomicAdd(&lcnt[ed[i] >> 9], 1);
            } else ed[i] = -1;
        }
        __syncthreads();
        for (int i = tid; i < NBUCK; i += 256)
            lbase[i] = atomicAdd(&gcur[i], lcnt[i]);
        __syncthreads();
        #pragma unroll
        for (int i = 0; i < 16; ++i) {
            if (ed[i] < 0) continue;
            int b = ed[i] >> 9;
            int idx = lbase[b] + er[i];
            if (idx < BCAP)
                bkt[size_t(b) * BCAP + idx] =
                    ((uint32_t)es[i] << 9) | (uint32_t)(ed[i] & 511);
        }
    } else if (bx < PB_BUCKET + PB_CVTX) {
        // ---- x fp32 -> bf16, 4 floats/thread ----
        size_t i = (size_t)((bx - PB_BUCKET) * 256 + tid) * 4;
        float4 f = *reinterpret_cast<const float4*>(&x[i]);
        uint2 o = make_uint2(pack2(f.x, f.y), pack2(f.z, f.w));
        *reinterpret_cast<uint2*>(&xb[i]) = o;
    } else if (bx < PB_BUCKET + PB_CVTX + PB_CVTW) {
        // ---- transpose W[K][128] fp32 -> WT[n*K+k] bf16 ----
        int idx = (bx - PB_BUCKET - PB_CVTX) * 256 + tid;   // 57344 total
        const float* W; uint16_t* T; int K; int local;
        if (idx < 8192)        { W = W1a; T = T1a; K = 64;  local = idx; }
        else if (idx < 24576)  { W = W1b; T = T1b; K = 128; local = idx - 8192; }
        else if (idx < 40960)  { W = W2a; T = T2a; K = 128; local = idx - 24576; }
        else                   { W = W2b; T = T2b; K = 128; local = idx - 40960; }
        int k = local >> 7, n = local & 127;
        T[n * K + k] = f32_to_bf16(W[local]);
    } else {
        // ---- graph offsets via binary search (batch is sorted) ----
        for (int g = tid; g <= N_GRAPHS; g += 256) {
            int lo = 0, hi = N_NODES;
            while (lo < hi) {
                int mid = (lo + hi) >> 1;
                if (load_idx(bat, size_t(mid), wide) < g) lo = mid + 1; else hi = mid;
            }
            goff[g] = lo;
        }
    }
}

// ---- per-bucket LDS counting sort -> dense dst-sorted CSR ------------------
__launch_bounds__(256)
__global__ void sort_bucket(const uint32_t* __restrict__ bkt, const int* __restrict__ gcur,
                            uint32_t* __restrict__ csr, int* __restrict__ row,
                            int* __restrict__ cnt) {
    __shared__ int h[512];
    __shared__ int cur[512];
    __shared__ int sd[256];
    const int b = blockIdx.x, tid = threadIdx.x;
    int n = gcur[b]; n = n > BCAP ? BCAP : n;
    const uint32_t* eb = bkt + size_t(b) * BCAP;
    h[tid] = 0; h[tid + 256] = 0;
    __syncthreads();
    for (int i = tid; i < n; i += 256) atomicAdd(&h[eb[i] & 511u], 1);
    __syncthreads();
    const int a0 = h[2 * tid], a1 = h[2 * tid + 1];
    int s = a0 + a1;
    sd[tid] = s;
    __syncthreads();
    for (int off = 1; off < 256; off <<= 1) {
        int t = (tid >= off) ? sd[tid - off] : 0;
        __syncthreads();
        sd[tid] += t;
        __syncthreads();
    }
    const int base = sd[tid] - s;      // exclusive prefix over thread's 2 bins
    cur[2 * tid]     = base;
    cur[2 * tid + 1] = base + a0;
    const int node0 = b * 512;
    if (node0 + 2 * tid < N_NODES) {
        row[node0 + 2 * tid] = b * BCAP + base;
        cnt[node0 + 2 * tid] = a0;
    }
    if (node0 + 2 * tid + 1 < N_NODES) {
        row[node0 + 2 * tid + 1] = b * BCAP + base + a0;
        cnt[node0 + 2 * tid + 1] = a1;
    }
    __syncthreads();
    uint32_t* cb = csr + size_t(b) * BCAP;
    for (int i = tid; i < n; i += 256) {
        uint32_t e = eb[i];
        int p = atomicAdd(&cur[e & 511u], 1);
        cb[p] = e >> 9;
    }
}

// ---- aggregation: out[i] = x[i] + sum_{j->i} x[j]  (bf16 in/out, fp32 acc) -
// Neighbor loop unrolled x4 with independent loads -> 4x memory-level
// parallelism (the loop is latency-bound, not BW-bound).
template <int D>
__global__ void gin_aggregate(const uint16_t* __restrict__ xb, const int* __restrict__ row,
                              const int* __restrict__ cnt, const uint32_t* __restrict__ csr,
                              uint16_t* __restrict__ out) {
    constexpr int TPN = D / 8;                 // lanes per node (16B bf16 each)
    const int tid  = threadIdx.x;
    const int node = blockIdx.x * (256 / TPN) + tid / TPN;
    const int lane = tid % TPN;
    if (node >= N_NODES) return;
    const size_t off   = size_t(lane) * 8;
    const size_t rbase = size_t(node) * D + off;
    uint4 v = *reinterpret_cast<const uint4*>(&xb[rbase]);
    float a[8];
    unpack2(v.x, a[0], a[1]); unpack2(v.y, a[2], a[3]);
    unpack2(v.z, a[4], a[5]); unpack2(v.w, a[6], a[7]);
    const int c = cnt[node];
    const uint32_t* sl = csr + row[node];
    int p = 0;
    for (; p + 4 <= c; p += 4) {
        int j0 = (int)sl[p + 0];
        int j1 = (int)sl[p + 1];
        int j2 = (int)sl[p + 2];
        int j3 = (int)sl[p + 3];
        uint4 w0 = *reinterpret_cast<const uint4*>(&xb[size_t(j0) * D + off]);
        uint4 w1 = *reinterpret_cast<const uint4*>(&xb[size_t(j1) * D + off]);
        uint4 w2 = *reinterpret_cast<const uint4*>(&xb[size_t(j2) * D + off]);
        uint4 w3 = *reinterpret_cast<const uint4*>(&xb[size_t(j3) * D + off]);
        accum8(a, w0); accum8(a, w1); accum8(a, w2); accum8(a, w3);
    }
    for (; p < c; ++p) {
        int j = (int)sl[p];
        uint4 w = *reinterpret_cast<const uint4*>(&xb[size_t(j) * D + off]);
        accum8(a, w);
    }
    uint4 o = make_uint4(pack2(a[0], a[1]), pack2(a[2], a[3]),
                         pack2(a[4], a[5]), pack2(a[6], a[7]));
    *reinterpret_cast<uint4*>(&out[rbase]) = o;
}

// ---- fused conv MLP: out = relu( relu(A@Wa + ba) @ Wb + bb ) ---------------
// A[M,K1] bf16 row-major; Wa as WTa[n][k]; intermediate 128x128 bf16 tile
// lives in LDS between the two GEMMs; same tile reused to stage final stores.
// Frag maps (m89/m91-verified): A m=lane&15,k=quad*8+j ; D col=lane&15,
// row=quad*4+reg.
typedef __attribute__((ext_vector_type(8))) short short8;
typedef __attribute__((ext_vector_type(4))) float f32x4;

template <int K1>
__launch_bounds__(256, 3)
__global__ void gin_mlp(const uint16_t* __restrict__ A, const uint16_t* __restrict__ WTa,
                        const float* __restrict__ ba, const uint16_t* __restrict__ WTb,
                        const float* __restrict__ bb, uint16_t* __restrict__ out,
                        int M) {
    constexpr int TSTR = 136;                       // +8 halfword pad
    __shared__ uint16_t tile[128 * TSTR];           // 34 KB
    const int tid  = threadIdx.x;
    const int wave = tid >> 6;
    const int lane = tid & 63;
    const int lr   = lane & 15;
    const int q    = lane >> 4;
    const int m_base = blockIdx.x * 128 + wave * 32;
    const int trow   = wave * 32 + q * 4;           // first output row (local)

    // ---- GEMM1: A @ WTa -> tile (bias ba, relu) ----
    short8 afr1[2][K1 / 32];
    #pragma unroll
    for (int mt = 0; mt < 2; ++mt) {
        int row = m_base + mt * 16 + lr;
        row = row < M ? row : (M - 1);
        const uint16_t* ap = A + size_t(row) * K1 + q * 8;
        #pragma unroll
        for (int kb = 0; kb < K1 / 32; ++kb)
            afr1[mt][kb] = *reinterpret_cast<const short8*>(ap + kb * 32);
    }
    for (int nt = 0; nt < 8; ++nt) {
        const uint16_t* bp = WTa + size_t(nt * 16 + lr) * K1 + q * 8;
        f32x4 c0 = {0.f, 0.f, 0.f, 0.f};
        f32x4 c1 = {0.f, 0.f, 0.f, 0.f};
        #pragma unroll
        for (int kb = 0; kb < K1 / 32; ++kb) {
            short8 b = *reinterpret_cast<const short8*>(bp + kb * 32);
            c0 = __builtin_amdgcn_mfma_f32_16x16x32_bf16(afr1[0][kb], b, c0, 0, 0, 0);
            c1 = __builtin_amdgcn_mfma_f32_16x16x32_bf16(afr1[1][kb], b, c1, 0, 0, 0);
        }
        const float bv = ba[nt * 16 + lr];
        const int col = nt * 16 + lr;
        #pragma unroll
        for (int r = 0; r < 4; ++r) {
            float v0 = fmaxf(c0[r] + bv, 0.f);
            float v1 = fmaxf(c1[r] + bv, 0.f);
            tile[(trow + r) * TSTR + col]      = f32_to_bf16(v0);
            tile[(trow + 16 + r) * TSTR + col] = f32_to_bf16(v1);
        }
    }
    __syncthreads();

    // ---- A-fragments for GEMM2 from LDS tile ----
    short8 afr2[2][4];
    #pragma unroll
    for (int mt = 0; mt < 2; ++mt) {
        const int row = wave * 32 + mt * 16 + lr;
        #pragma unroll
        for (int kb = 0; kb < 4; ++kb)
            afr2[mt][kb] = *reinterpret_cast<const short8*>(
                &tile[row * TSTR + kb * 32 + q * 8]);
    }
    __syncthreads();   // tile will be overwritten by GEMM2 epilogue

    // ---- GEMM2: h1 @ WTb -> tile (bias bb, relu) ----
    for (int nt = 0; nt < 8; ++nt) {
        const uint16_t* bp = WTb + size_t(nt * 16 + lr) * 128 + q * 8;
        f32x4 c0 = {0.f, 0.f, 0.f, 0.f};
        f32x4 c1 = {0.f, 0.f, 0.f, 0.f};
        #pragma unroll
        for (int kb = 0; kb < 4; ++kb) {
            short8 b = *reinterpret_cast<const short8*>(bp + kb * 32);
            c0 = __builtin_amdgcn_mfma_f32_16x16x32_bf16(afr2[0][kb], b, c0, 0, 0, 0);
            c1 = __builtin_amdgcn_mfma_f32_16x16x32_bf16(afr2[1][kb], b, c1, 0, 0, 0);
        }
        const float bv = bb[nt * 16 + lr];
        const int col = nt * 16 + lr;
        #pragma unroll
        for (int r = 0; r < 4; ++r) {
            float v0 = fmaxf(c0[r] + bv, 0.f);
            float v1 = fmaxf(c1[r] + bv, 0.f);
            tile[(trow + r) * TSTR + col]      = f32_to_bf16(v0);
            tile[(trow + 16 + r) * TSTR + col] = f32_to_bf16(v1);
        }
    }
    __syncthreads();

    // ---- coalesced vectorized stores: 16 threads per row, 16B each ----
    const int c8 = (tid & 15) * 8;
    for (int rr = tid >> 4; rr < 128; rr += 16) {
        int grow = blockIdx.x * 128 + rr;
        if (grow < M)
            *reinterpret_cast<uint4*>(&out[size_t(grow) * 128 + c8]) =
                *reinterpret_cast<const uint4*>(&tile[rr * TSTR + c8]);
    }
}

// ---- fused mean-pool + dot(Wc) + bc ---------------------------------------
__global__ void pool_out(const uint16_t* __restrict__ h2, const int* __restrict__ goff,
                         const float* __restrict__ Wc, const float* __restrict__ bc,
                         float* __restrict__ out) {
    __shared__ float red[256];
    const int g    = blockIdx.x;
    const int tid  = threadIdx.x;
    const int d    = tid & 127;
    const int half = tid >> 7;
    const int s = goff[g], e = goff[g + 1];
    float acc = 0.f;
    for (int n = s + half; n < e; n += 2)
        acc += bf16_to_f32(h2[size_t(n) * 128 + d]);
    acc *= Wc[d];
    red[tid] = acc;
    __syncthreads();
    for (int off = 128; off > 0; off >>= 1) {
        if (tid < off) red[tid] += red[tid + off];
        __syncthreads();
    }
    if (tid == 0) {
        int c2 = e - s;
        float m = (c2 > 0) ? (red[0] / (float)c2) : 0.f;
        out[g] = m + bc[0];
    }
}

}  // namespace

extern "C" void kernel_launch(void* const* d_in, const int* in_sizes, int n_in,
                              void* d_out, int out_size, void* d_ws, size_t ws_size,
                              hipStream_t stream) {
    (void)in_sizes; (void)n_in; (void)out_size;
    if (ws_size < WS_NEED) return;

    const float* x   = (const float*)d_in[0];
    const void*  ei  = d_in[1];
    const void*  bat = d_in[2];
    const float* W1a = (const float*)d_in[3];
    const float* b1a = (const float*)d_in[4];
    const float* W1b = (const float*)d_in[5];
    const float* b1b = (const float*)d_in[6];
    const float* W2a = (const float*)d_in[7];
    const float* b2a = (const float*)d_in[8];
    const float* W2b = (const float*)d_in[9];
    const float* b2b = (const float*)d_in[10];
    const float* Wc  = (const float*)d_in[11];
    const float* bc  = (const float*)d_in[12];
    float* out = (float*)d_out;

    char* ws = (char*)d_ws;
    int*      cnt  = (int*)(ws + OFF_CNT);
    int*      row  = (int*)(ws + OFF_ROW);
    int*      goff = (int*)(ws + OFF_GOFF);
    int*      flg  = (int*)(ws + OFF_FLAG);
    int*      gcur = (int*)(ws + OFF_GCUR);
    uint32_t* bkt  = (uint32_t*)(ws + OFF_BKT);
    uint32_t* csr  = (uint32_t*)(ws + OFF_CSR);
    uint16_t* xb   = (uint16_t*)(ws + OFF_XB);
    uint16_t* T1a  = (uint16_t*)(ws + OFF_WT1A);
    uint16_t* T1b  = (uint16_t*)(ws + OFF_WT1B);
    uint16_t* T2a  = (uint16_t*)(ws + OFF_WT2A);
    uint16_t* T2b  = (uint16_t*)(ws + OFF_WT2B);
    uint16_t* F0   = (uint16_t*)(ws + OFF_F0);
    uint16_t* H1   = (uint16_t*)(ws + OFF_H1);
    uint16_t* H2   = (uint16_t*)(ws + OFF_H2);

    hipMemsetAsync(flg, 0, 4, stream);
    hipMemsetAsync(gcur, 0, size_t(NBUCK) * 4, stream);

    detect_wide<<<1, 256, 0, stream>>>((const int*)ei, flg);

    // fused prep: bucket + cvt_x + cvt_weights + goff
    prep<<<PB_TOTAL, 256, 0, stream>>>(ei, bat, flg, x, W1a, W1b, W2a, W2b,
                                       gcur, bkt, xb, T1a, T1b, T2a, T2b, goff);
    sort_bucket<<<NBUCK, 256, 0, stream>>>(bkt, gcur, csr, row, cnt);

    constexpr int GEMM_GRID = (N_NODES + 127) / 128;   // 782

    // conv1
    gin_aggregate<64><<<(N_NODES + 31) / 32, 256, 0, stream>>>(xb, row, cnt, csr, F0);
    gin_mlp<64><<<GEMM_GRID, 256, 0, stream>>>(F0, T1a, b1a, T1b, b1b, H1, N_NODES);
    // conv2
    gin_aggregate<128><<<(N_NODES + 15) / 16, 256, 0, stream>>>(H1, row, cnt, csr, H2);
    gin_mlp<128><<<GEMM_GRID, 256, 0, stream>>>(H2, T2a, b2a, T2b, b2b, H1, N_NODES);
    // pool + head
    pool_out<<<N_GRAPHS, 256, 0, stream>>>(H1, goff, Wc, bc, out);
}